// Round 3
// baseline (9411.733 us; speedup 1.0000x reference)
//
#include <hip/hip_runtime.h>
#include <hip/hip_bf16.h>
#include <hip/hip_cooperative_groups.h>

// LSTM: B=1024, SEQ=128, H=1024, NCLS=10, IN_DIM=1.
// Persistent cooperative kernel (256 WG x 256 thr, 1 WG/CU), grid.sync per
// timestep. c-state in registers; fp16 MFMA 16x16x32; double-buffered LDS
// (exactly 64 KiB); x transposed to global scratch, prefetched to registers.
// Fallback: if cooperative launch fails, per-step launches (Round-1 style).

#define HDIM 1024
#define SEQ 128
#define NCLS 10

namespace cg = cooperative_groups;

using half8   = __attribute__((ext_vector_type(8))) _Float16;
using floatx4 = __attribute__((ext_vector_type(4))) float;

#define GLOBAL_AS const __attribute__((address_space(1))) void*
#define LDS_AS __attribute__((address_space(3))) void*

__device__ __forceinline__ float fast_sig(float x) {
    return __builtin_amdgcn_rcpf(1.f + __expf(-x));
}
__device__ __forceinline__ float fast_tanh(float x) {
    return 1.f - 2.f * __builtin_amdgcn_rcpf(__expf(2.f * x) + 1.f);
}

// ---------------------------------------------------------------------------
// Prepack weights, gate-interleaved: packed row c of u-slice holds
// half=c>>6, gate=(c>>4)&3, ul=c&15 -> unit j = u*32 + half*16 + ul.
// ---------------------------------------------------------------------------
__global__ void prepack_kernel(const float* __restrict__ wgh,
                               const float* __restrict__ wih,
                               const float* __restrict__ wfh,
                               const float* __restrict__ woh,
                               _Float16* __restrict__ Wp) {
    int p = blockIdx.x;                 // 0..4095
    int u = p >> 7, c = p & 127;
    int half_ = c >> 6, g = (c >> 4) & 3, ul = c & 15;
    int j = u * 32 + half_ * 16 + ul;
    const float* src = (g == 0) ? wgh : (g == 1) ? wih : (g == 2) ? wfh : woh;
    src += (size_t)j * HDIM;
    int k = threadIdx.x * 4;
    float4 v = *(const float4*)(src + k);
    union { _Float16 h[4]; uint2 u2; } cv;
    cv.h[0] = (_Float16)v.x; cv.h[1] = (_Float16)v.y;
    cv.h[2] = (_Float16)v.z; cv.h[3] = (_Float16)v.w;
    *(uint2*)(Wp + (size_t)p * HDIM + k) = cv.u2;
}

__global__ void transpose_x(const float* __restrict__ x, float* __restrict__ xT) {
    int b = blockIdx.x;          // 0..1023
    int t = threadIdx.x;         // 0..127
    xT[t * 1024 + b] = x[b * SEQ + t];
}

// ---------------------------------------------------------------------------
// Persistent cooperative LSTM. WG tile 128 batch x 128 gate-cols; 2x2 waves
// of 64x64. LDS: dbuf BK=64 tiles, XOR-swizzled (slot ^= row&7), 64 KiB.
// ---------------------------------------------------------------------------
__global__ __launch_bounds__(256, 1) void lstm_persist(
    _Float16* __restrict__ hbuf0, _Float16* __restrict__ hbuf1,
    const _Float16* __restrict__ Wp, const float* __restrict__ xT,
    const float* __restrict__ wgx, const float* __restrict__ wix,
    const float* __restrict__ wfx, const float* __restrict__ wox,
    const float* __restrict__ bg, const float* __restrict__ bi,
    const float* __restrict__ bf, const float* __restrict__ bo,
    const float* __restrict__ wph, const float* __restrict__ bp,
    float* __restrict__ out)
{
    __shared__ _Float16 lA[2][128 * 64];   // 2 x 16 KB
    __shared__ _Float16 lB[2][128 * 64];   // 2 x 16 KB  (total 64 KiB)

    const int blk = blockIdx.x;
    const int u   = (blk & 7) * 4 + ((blk >> 3) & 3);  // unit-tile, XCD-local
    const int bc  = blk >> 5;
    const int b0  = bc * 128;
    const int tid = threadIdx.x;
    const int wv  = tid >> 6;
    const int l   = tid & 63;
    const int lane15 = l & 15;
    const int quad   = l >> 4;
    const int rf     = lane15 & 7;
    const int wr = wv >> 1, wc = wv & 1;

    // epilogue constants: this lane's unit j (cols wc*64.. hold 4 gates of j)
    const int j = u * 32 + wc * 16 + lane15;
    const float wgx_ = wgx[j], wix_ = wix[j], wfx_ = wfx[j], wox_ = wox[j];
    const float bg_ = bg[j], bi_ = bi[j], bf_ = bf[j], bo_ = bo[j];

    // staging: per wave 4 instrs/tile; 1 instr = 8 rows x 128 B
    int goff[4], ldst[4];
    const int kb = (l & 7) ^ (l >> 3);
    #pragma unroll
    for (int i = 0; i < 4; ++i) {
        int rowb = wv * 32 + i * 8;
        goff[i] = (rowb + (l >> 3)) * HDIM + kb * 8;
        ldst[i] = rowb * 64 + l * 8;
    }

    const _Float16* WpBase = Wp + (size_t)u * 128 * HDIM;

    cg::grid_group grid = cg::this_grid();

    float creg[4][4];
    #pragma unroll
    for (int a = 0; a < 4; ++a)
        #pragma unroll
        for (int b = 0; b < 4; ++b) creg[a][b] = 0.f;

    #pragma unroll 1
    for (int t = 0; t < SEQ; ++t) {
        // prefetch this thread's 16 x values (lane15-uniform -> broadcast)
        float xr[4][4];
        #pragma unroll
        for (int mt = 0; mt < 4; ++mt)
            #pragma unroll
            for (int r = 0; r < 4; ++r)
                xr[mt][r] = xT[t * 1024 + b0 + wr * 64 + mt * 16 + quad * 4 + r];

        floatx4 acc[4][4] = {};
        if (t > 0) {
            const _Float16* hprev = (t & 1) ? hbuf0 : hbuf1;
            const _Float16* Abase = hprev + (size_t)b0 * HDIM;

            // prologue: stage kt=0 into buffer 0
            #pragma unroll
            for (int i = 0; i < 4; ++i) {
                __builtin_amdgcn_global_load_lds((GLOBAL_AS)(Abase + goff[i]),
                                                 (LDS_AS)(&lA[0][ldst[i]]), 16, 0, 0);
                __builtin_amdgcn_global_load_lds((GLOBAL_AS)(WpBase + goff[i]),
                                                 (LDS_AS)(&lB[0][ldst[i]]), 16, 0, 0);
            }
            __syncthreads();

            #pragma unroll 2
            for (int kt = 0; kt < 16; ++kt) {
                const int cur = kt & 1;
                if (kt < 15) {
                    const int k0 = (kt + 1) * 64;
                    #pragma unroll
                    for (int i = 0; i < 4; ++i) {
                        __builtin_amdgcn_global_load_lds(
                            (GLOBAL_AS)(Abase + goff[i] + k0),
                            (LDS_AS)(&lA[1 - cur][ldst[i]]), 16, 0, 0);
                        __builtin_amdgcn_global_load_lds(
                            (GLOBAL_AS)(WpBase + goff[i] + k0),
                            (LDS_AS)(&lB[1 - cur][ldst[i]]), 16, 0, 0);
                    }
                }
                const _Float16* bufA = &lA[cur][0];
                const _Float16* bufB = &lB[cur][0];
                #pragma unroll
                for (int kc = 0; kc < 2; ++kc) {
                    const int slot = ((kc * 4 + quad) ^ rf) * 8;
                    half8 afr[4], bfr[4];
                    #pragma unroll
                    for (int mt = 0; mt < 4; ++mt)
                        afr[mt] = *(const half8*)(bufA + (wr * 64 + mt * 16 + lane15) * 64 + slot);
                    #pragma unroll
                    for (int nt = 0; nt < 4; ++nt)
                        bfr[nt] = *(const half8*)(bufB + (wc * 64 + nt * 16 + lane15) * 64 + slot);
                    #pragma unroll
                    for (int mt = 0; mt < 4; ++mt)
                        #pragma unroll
                        for (int nt = 0; nt < 4; ++nt)
                            acc[mt][nt] = __builtin_amdgcn_mfma_f32_16x16x32_f16(
                                afr[mt], bfr[nt], acc[mt][nt], 0, 0, 0);
                }
                __syncthreads();   // drains stage(kt+1) vmem + this kt's ds reads
            }
        }

        // fused LSTM cell epilogue (c in registers; gates register-local)
        _Float16* hw = (t & 1) ? hbuf1 : hbuf0;
        #pragma unroll
        for (int mt = 0; mt < 4; ++mt) {
            #pragma unroll
            for (int r = 0; r < 4; ++r) {
                const int m = wr * 64 + mt * 16 + quad * 4 + r;
                const float xt = xr[mt][r];
                float pg = acc[mt][0][r] + xt * wgx_ + bg_;
                float pi = acc[mt][1][r] + xt * wix_ + bi_;
                float pf = acc[mt][2][r] + xt * wfx_ + bf_;
                float po = acc[mt][3][r] + xt * wox_ + bo_;
                float g  = fast_tanh(pg);
                float ii = fast_sig(pi);
                float ff = fast_sig(pf);
                float oo = fast_sig(po);
                float cn = g * ii + creg[mt][r] * ff;
                creg[mt][r] = cn;
                hw[(size_t)(b0 + m) * HDIM + j] = (_Float16)(fast_tanh(cn) * oo);
            }
        }
        __threadfence();
        grid.sync();
    }

    // logits: wave w -> batch row w; h_last is hbuf1 (t=127 odd)
    {
        const int w = blk * 4 + wv;
        float accv[NCLS];
        #pragma unroll
        for (int cc = 0; cc < NCLS; ++cc) accv[cc] = 0.f;
        for (int k = l; k < HDIM; k += 64) {
            float hv = (float)hbuf1[(size_t)w * HDIM + k];
            #pragma unroll
            for (int cc = 0; cc < NCLS; ++cc)
                accv[cc] += hv * wph[cc * HDIM + k];
        }
        #pragma unroll
        for (int cc = 0; cc < NCLS; ++cc) {
            float v = accv[cc];
            #pragma unroll
            for (int off = 32; off > 0; off >>= 1)
                v += __shfl_down(v, off, 64);
            if (l == 0) out[w * NCLS + cc] = v + bp[cc];
        }
    }
}

// ---------------------------------------------------------------------------
// Fallback path (Round-1 proven structure, interleaved Wp layout).
// ---------------------------------------------------------------------------
__global__ __launch_bounds__(256) void lstm_step_fb(
    const _Float16* __restrict__ h_in, _Float16* __restrict__ h_out,
    float* __restrict__ c_state, const _Float16* __restrict__ Wp,
    const float* __restrict__ x, int t,
    const float* __restrict__ wgx, const float* __restrict__ wix,
    const float* __restrict__ wfx, const float* __restrict__ wox,
    const float* __restrict__ bg, const float* __restrict__ bi,
    const float* __restrict__ bf, const float* __restrict__ bo)
{
    __shared__ _Float16 lA[128 * 64];
    __shared__ _Float16 lB[128 * 64];
    __shared__ float lxt[128];

    const int blk = blockIdx.x;
    const int u  = (blk & 7) * 4 + ((blk >> 3) & 3);
    const int bc = blk >> 5;
    const int b0 = bc * 128;
    const int tid = threadIdx.x;
    const int wv = tid >> 6;
    const int l  = tid & 63;

    if (tid < 128) lxt[tid] = x[(size_t)(b0 + tid) * SEQ + t];

    floatx4 acc[2][8] = {};
    const _Float16* Abase = h_in + (size_t)b0 * HDIM;
    const _Float16* Bbase = Wp + (size_t)u * 128 * HDIM;

    const int rl   = l >> 3;
    const int kb   = (l & 7) ^ rl;
    const int lane15 = l & 15;
    const int quad   = l >> 4;
    const int rf     = lane15 & 7;

    for (int kt = 0; kt < 16; ++kt) {
        const int k0 = kt * 64;
        __syncthreads();
        #pragma unroll
        for (int cq = 0; cq < 4; ++cq) {
            int q = wv * 4 + cq;
            int row = q * 8 + rl;
            __builtin_amdgcn_global_load_lds(
                (GLOBAL_AS)(Abase + (size_t)row * HDIM + k0 + kb * 8),
                (LDS_AS)(lA + q * 512 + l * 8), 16, 0, 0);
            __builtin_amdgcn_global_load_lds(
                (GLOBAL_AS)(Bbase + (size_t)row * HDIM + k0 + kb * 8),
                (LDS_AS)(lB + q * 512 + l * 8), 16, 0, 0);
        }
        __syncthreads();

        #pragma unroll
        for (int kc = 0; kc < 2; ++kc) {
            const int slot = ((kc * 4 + quad) ^ rf) * 8;
            half8 afr[2], bfr[8];
            #pragma unroll
            for (int mi = 0; mi < 2; ++mi)
                afr[mi] = *(const half8*)(lA + (wv * 32 + mi * 16 + lane15) * 64 + slot);
            #pragma unroll
            for (int ni = 0; ni < 8; ++ni)
                bfr[ni] = *(const half8*)(lB + (ni * 16 + lane15) * 64 + slot);
            #pragma unroll
            for (int mi = 0; mi < 2; ++mi)
                #pragma unroll
                for (int ni = 0; ni < 8; ++ni)
                    acc[mi][ni] = __builtin_amdgcn_mfma_f32_16x16x32_f16(
                        afr[mi], bfr[ni], acc[mi][ni], 0, 0, 0);
        }
    }

    #pragma unroll
    for (int p = 0; p < 2; ++p) {
        const int j = u * 32 + p * 16 + lane15;
        const float wg_ = wgx[j], wi_ = wix[j], wf_ = wfx[j], wo_ = wox[j];
        const float bgv = bg[j], biv = bi[j], bfv = bf[j], bov = bo[j];
        #pragma unroll
        for (int mi = 0; mi < 2; ++mi) {
            #pragma unroll
            for (int r = 0; r < 4; ++r) {
                const int m = wv * 32 + mi * 16 + quad * 4 + r;
                const float xt = lxt[m];
                const size_t idx = (size_t)(b0 + m) * HDIM + j;
                float pg = acc[mi][p * 4 + 0][r] + xt * wg_ + bgv;
                float pi = acc[mi][p * 4 + 1][r] + xt * wi_ + biv;
                float pf = acc[mi][p * 4 + 2][r] + xt * wf_ + bfv;
                float po = acc[mi][p * 4 + 3][r] + xt * wo_ + bov;
                float g  = fast_tanh(pg);
                float ii = fast_sig(pi);
                float ff = fast_sig(pf);
                float oo = fast_sig(po);
                float cn = g * ii + c_state[idx] * ff;
                c_state[idx] = cn;
                h_out[idx] = (_Float16)(fast_tanh(cn) * oo);
            }
        }
    }
}

__global__ void logits_fb(const _Float16* __restrict__ h,
                          const float* __restrict__ wph,
                          const float* __restrict__ bp,
                          float* __restrict__ out) {
    const int w = (blockIdx.x * blockDim.x + threadIdx.x) >> 6;
    const int l = threadIdx.x & 63;
    float accv[NCLS];
    #pragma unroll
    for (int c = 0; c < NCLS; ++c) accv[c] = 0.f;
    for (int k = l; k < HDIM; k += 64) {
        float hv = (float)h[(size_t)w * HDIM + k];
        #pragma unroll
        for (int c = 0; c < NCLS; ++c)
            accv[c] += hv * wph[c * HDIM + k];
    }
    #pragma unroll
    for (int c = 0; c < NCLS; ++c) {
        float v = accv[c];
        #pragma unroll
        for (int off = 32; off > 0; off >>= 1)
            v += __shfl_down(v, off, 64);
        if (l == 0) out[w * NCLS + c] = v + bp[c];
    }
}

extern "C" void kernel_launch(void* const* d_in, const int* in_sizes, int n_in,
                              void* d_out, int out_size, void* d_ws, size_t ws_size,
                              hipStream_t stream) {
    const float* x   = (const float*)d_in[0];
    const float* wgx = (const float*)d_in[1];
    const float* wgh = (const float*)d_in[2];
    const float* wix = (const float*)d_in[3];
    const float* wih = (const float*)d_in[4];
    const float* wfx = (const float*)d_in[5];
    const float* wfh = (const float*)d_in[6];
    const float* wox = (const float*)d_in[7];
    const float* woh = (const float*)d_in[8];
    const float* wph = (const float*)d_in[9];
    const float* bg  = (const float*)d_in[10];
    const float* bi  = (const float*)d_in[11];
    const float* bf  = (const float*)d_in[12];
    const float* bo  = (const float*)d_in[13];
    const float* bp  = (const float*)d_in[14];
    float* out = (float*)d_out;

    char* ws = (char*)d_ws;
    _Float16* Wp    = (_Float16*)(ws);               // 0..8 MB
    _Float16* hbuf0 = (_Float16*)(ws + (8u << 20));  // 8..10 MB
    _Float16* hbuf1 = (_Float16*)(ws + (10u << 20)); // 10..12 MB
    float*    xT    = (float*)(ws + (12u << 20));    // 12..12.5 MB (coop only)
    float*    cst   = (float*)(ws + (12u << 20));    // 12..16 MB (fallback only)

    prepack_kernel<<<4096, 256, 0, stream>>>(wgh, wih, wfh, woh, Wp);
    transpose_x<<<1024, 128, 0, stream>>>(x, xT);

    void* args[] = { (void*)&hbuf0, (void*)&hbuf1, (void*)&Wp, (void*)&xT,
                     (void*)&wgx, (void*)&wix, (void*)&wfx, (void*)&wox,
                     (void*)&bg, (void*)&bi, (void*)&bf, (void*)&bo,
                     (void*)&wph, (void*)&bp, (void*)&out };
    hipError_t err = hipLaunchCooperativeKernel((const void*)lstm_persist,
                                                dim3(256), dim3(256),
                                                args, 0, stream);
    if (err != hipSuccess) {
        (void)hipGetLastError();   // clear error state
        hipMemsetAsync(cst, 0, 4u << 20, stream);
        hipMemsetAsync(hbuf0, 0, 2u << 20, stream);
        _Float16* hin = hbuf0;
        _Float16* hout = hbuf1;
        for (int t = 0; t < SEQ; ++t) {
            lstm_step_fb<<<256, 256, 0, stream>>>(hin, hout, cst, Wp, x, t,
                                                  wgx, wix, wfx, wox,
                                                  bg, bi, bf, bo);
            _Float16* tmp = hin; hin = hout; hout = tmp;
        }
        logits_fb<<<256, 256, 0, stream>>>(hin, wph, bp, out);
    }
}

// Round 4
// 2754.077 us; speedup vs baseline: 3.4174x; 3.4174x over previous
//
#include <hip/hip_runtime.h>
#include <hip/hip_bf16.h>

// LSTM: B=1024, SEQ=128, H=1024, NCLS=10, IN_DIM=1.
// Per-step kernel launches (grid sync via kernel boundary — measured cheaper
// than cooperative grid.sync on non-coherent-L2 CDNA4).
// fp16 MFMA 16x16x32, 128x128 block tile, 2x2 waves of 64x64 (4x4 acc),
// double-buffered BK=64 LDS (64 KiB), XOR-swizzled staging via
// global_load_lds width=16. fp32 cell state, fast exp-based activations.

#define HDIM 1024
#define SEQ 128
#define NCLS 10

using half8   = __attribute__((ext_vector_type(8))) _Float16;
using floatx4 = __attribute__((ext_vector_type(4))) float;

#define GLOBAL_AS const __attribute__((address_space(1))) void*
#define LDS_AS __attribute__((address_space(3))) void*

__device__ __forceinline__ float fast_sig(float x) {
    return __builtin_amdgcn_rcpf(1.f + __expf(-x));
}
__device__ __forceinline__ float fast_tanh(float x) {
    return 1.f - 2.f * __builtin_amdgcn_rcpf(__expf(2.f * x) + 1.f);
}

// ---------------------------------------------------------------------------
// Prepack weights fp32->fp16, gate-interleaved: packed row c of u-slice:
// half=c>>6, gate=(c>>4)&3, ul=c&15 -> unit j = u*32 + half*16 + ul.
// Wave wc (col half) then holds all 4 gates of unit j register-locally.
// ---------------------------------------------------------------------------
__global__ void prepack_kernel(const float* __restrict__ wgh,
                               const float* __restrict__ wih,
                               const float* __restrict__ wfh,
                               const float* __restrict__ woh,
                               _Float16* __restrict__ Wp) {
    int p = blockIdx.x;                 // 0..4095
    int u = p >> 7, c = p & 127;
    int half_ = c >> 6, g = (c >> 4) & 3, ul = c & 15;
    int j = u * 32 + half_ * 16 + ul;
    const float* src = (g == 0) ? wgh : (g == 1) ? wih : (g == 2) ? wfh : woh;
    src += (size_t)j * HDIM;
    int k = threadIdx.x * 4;
    float4 v = *(const float4*)(src + k);
    union { _Float16 h[4]; uint2 u2; } cv;
    cv.h[0] = (_Float16)v.x; cv.h[1] = (_Float16)v.y;
    cv.h[2] = (_Float16)v.z; cv.h[3] = (_Float16)v.w;
    *(uint2*)(Wp + (size_t)p * HDIM + k) = cv.u2;
}

// ---------------------------------------------------------------------------
// One LSTM step. 256 WGs x 256 thr (1/CU). Tile 128 batch x 128 gate-cols.
// t==0: GEMM skipped, c treated as zero (no memset needed anywhere).
// ---------------------------------------------------------------------------
__global__ __launch_bounds__(256) void lstm_step(
    const _Float16* __restrict__ h_in, _Float16* __restrict__ h_out,
    float* __restrict__ c_state, const _Float16* __restrict__ Wp,
    const float* __restrict__ x, int t,
    const float* __restrict__ wgx, const float* __restrict__ wix,
    const float* __restrict__ wfx, const float* __restrict__ wox,
    const float* __restrict__ bg, const float* __restrict__ bi,
    const float* __restrict__ bf, const float* __restrict__ bo)
{
    __shared__ _Float16 lA[2][128 * 64];   // 2 x 16 KB
    __shared__ _Float16 lB[2][128 * 64];   // 2 x 16 KB  (64 KiB total)

    const int blk = blockIdx.x;
    const int u   = (blk & 7) * 4 + ((blk >> 3) & 3);  // unit-tile, XCD-local
    const int bc  = blk >> 5;
    const int b0  = bc * 128;
    const int tid = threadIdx.x;
    const int wv  = tid >> 6;
    const int l   = tid & 63;
    const int lane15 = l & 15;
    const int quad   = l >> 4;
    const int rf     = lane15 & 7;
    const int wr = wv >> 1, wc = wv & 1;

    // this lane's unit j; epilogue constants
    const int j = u * 32 + wc * 16 + lane15;
    const float wgx_ = wgx[j], wix_ = wix[j], wfx_ = wfx[j], wox_ = wox[j];
    const float bg_ = bg[j], bi_ = bi[j], bf_ = bf[j], bo_ = bo[j];

    // prefetch c-state and x (latency hidden under staging/GEMM)
    float creg[4][4];
    float xr[4][4];
    #pragma unroll
    for (int mt = 0; mt < 4; ++mt) {
        #pragma unroll
        for (int r = 0; r < 4; ++r) {
            const int m = wr * 64 + mt * 16 + quad * 4 + r;
            xr[mt][r] = x[(size_t)(b0 + m) * SEQ + t];
            creg[mt][r] = (t > 0) ? c_state[(size_t)(b0 + m) * HDIM + j] : 0.f;
        }
    }

    // staging: per wave 4 global_load_lds per tile; 1 instr = 8 rows x 16 B
    int goff[4], ldst[4];
    const int kb = (l & 7) ^ (l >> 3);
    #pragma unroll
    for (int i = 0; i < 4; ++i) {
        int rowb = wv * 32 + i * 8;
        goff[i] = (rowb + (l >> 3)) * HDIM + kb * 8;
        ldst[i] = rowb * 64 + l * 8;
    }

    floatx4 acc[4][4] = {};

    if (t > 0) {
        const _Float16* Abase = h_in + (size_t)b0 * HDIM;
        const _Float16* Bbase = Wp + (size_t)u * 128 * HDIM;

        // prologue: stage kt=0 into buffer 0
        #pragma unroll
        for (int i = 0; i < 4; ++i) {
            __builtin_amdgcn_global_load_lds((GLOBAL_AS)(Abase + goff[i]),
                                             (LDS_AS)(&lA[0][ldst[i]]), 16, 0, 0);
            __builtin_amdgcn_global_load_lds((GLOBAL_AS)(Bbase + goff[i]),
                                             (LDS_AS)(&lB[0][ldst[i]]), 16, 0, 0);
        }
        __syncthreads();

        #pragma unroll 2
        for (int kt = 0; kt < 16; ++kt) {
            const int cur = kt & 1;
            if (kt < 15) {
                const int k0 = (kt + 1) * 64;
                #pragma unroll
                for (int i = 0; i < 4; ++i) {
                    __builtin_amdgcn_global_load_lds(
                        (GLOBAL_AS)(Abase + goff[i] + k0),
                        (LDS_AS)(&lA[1 - cur][ldst[i]]), 16, 0, 0);
                    __builtin_amdgcn_global_load_lds(
                        (GLOBAL_AS)(Bbase + goff[i] + k0),
                        (LDS_AS)(&lB[1 - cur][ldst[i]]), 16, 0, 0);
                }
            }
            const _Float16* bufA = &lA[cur][0];
            const _Float16* bufB = &lB[cur][0];
            #pragma unroll
            for (int kc = 0; kc < 2; ++kc) {
                const int slot = ((kc * 4 + quad) ^ rf) * 8;
                half8 afr[4], bfr[4];
                #pragma unroll
                for (int mt = 0; mt < 4; ++mt)
                    afr[mt] = *(const half8*)(bufA + (wr * 64 + mt * 16 + lane15) * 64 + slot);
                #pragma unroll
                for (int nt = 0; nt < 4; ++nt)
                    bfr[nt] = *(const half8*)(bufB + (wc * 64 + nt * 16 + lane15) * 64 + slot);
                #pragma unroll
                for (int mt = 0; mt < 4; ++mt)
                    #pragma unroll
                    for (int nt = 0; nt < 4; ++nt)
                        acc[mt][nt] = __builtin_amdgcn_mfma_f32_16x16x32_f16(
                            afr[mt], bfr[nt], acc[mt][nt], 0, 0, 0);
            }
            __syncthreads();
        }
    }

    // fused LSTM cell epilogue: lane holds all 4 gates of (batch m, unit j)
    #pragma unroll
    for (int mt = 0; mt < 4; ++mt) {
        #pragma unroll
        for (int r = 0; r < 4; ++r) {
            const int m = wr * 64 + mt * 16 + quad * 4 + r;
            const float xt = xr[mt][r];
            const size_t idx = (size_t)(b0 + m) * HDIM + j;
            float pg = acc[mt][0][r] + xt * wgx_ + bg_;
            float pi = acc[mt][1][r] + xt * wix_ + bi_;
            float pf = acc[mt][2][r] + xt * wfx_ + bf_;
            float po = acc[mt][3][r] + xt * wox_ + bo_;
            float g  = fast_tanh(pg);
            float ii = fast_sig(pi);
            float ff = fast_sig(pf);
            float oo = fast_sig(po);
            float cn = g * ii + creg[mt][r] * ff;
            c_state[idx] = cn;
            h_out[idx] = (_Float16)(fast_tanh(cn) * oo);
        }
    }
}

// ---------------------------------------------------------------------------
// logits = h_last @ w_ph^T + bias_p. One wave per batch row.
// ---------------------------------------------------------------------------
__global__ void logits_kernel(const _Float16* __restrict__ h,
                              const float* __restrict__ wph,
                              const float* __restrict__ bp,
                              float* __restrict__ out) {
    const int w = (blockIdx.x * blockDim.x + threadIdx.x) >> 6; // 0..1023
    const int l = threadIdx.x & 63;
    float accv[NCLS];
    #pragma unroll
    for (int c = 0; c < NCLS; ++c) accv[c] = 0.f;
    for (int k = l; k < HDIM; k += 64) {
        float hv = (float)h[(size_t)w * HDIM + k];
        #pragma unroll
        for (int c = 0; c < NCLS; ++c)
            accv[c] += hv * wph[c * HDIM + k];
    }
    #pragma unroll
    for (int c = 0; c < NCLS; ++c) {
        float v = accv[c];
        #pragma unroll
        for (int off = 32; off > 0; off >>= 1)
            v += __shfl_down(v, off, 64);
        if (l == 0) out[w * NCLS + c] = v + bp[c];
    }
}

extern "C" void kernel_launch(void* const* d_in, const int* in_sizes, int n_in,
                              void* d_out, int out_size, void* d_ws, size_t ws_size,
                              hipStream_t stream) {
    const float* x   = (const float*)d_in[0];
    const float* wgx = (const float*)d_in[1];
    const float* wgh = (const float*)d_in[2];
    const float* wix = (const float*)d_in[3];
    const float* wih = (const float*)d_in[4];
    const float* wfx = (const float*)d_in[5];
    const float* wfh = (const float*)d_in[6];
    const float* wox = (const float*)d_in[7];
    const float* woh = (const float*)d_in[8];
    const float* wph = (const float*)d_in[9];
    const float* bg  = (const float*)d_in[10];
    const float* bi  = (const float*)d_in[11];
    const float* bf  = (const float*)d_in[12];
    const float* bo  = (const float*)d_in[13];
    const float* bp  = (const float*)d_in[14];
    float* out = (float*)d_out;

    char* ws = (char*)d_ws;
    _Float16* Wp    = (_Float16*)(ws);               // 0..8 MB
    _Float16* hbuf0 = (_Float16*)(ws + (8u << 20));  // 8..10 MB
    _Float16* hbuf1 = (_Float16*)(ws + (10u << 20)); // 10..12 MB
    float*    cst   = (float*)(ws + (12u << 20));    // 12..16 MB

    prepack_kernel<<<4096, 256, 0, stream>>>(wgh, wih, wfh, woh, Wp);

    _Float16* hin = hbuf0;   // unread at t=0 (GEMM skipped)
    _Float16* hout = hbuf0;
    for (int t = 0; t < SEQ; ++t) {
        hin  = (t & 1) ? hbuf0 : hbuf1;   // t=0 value irrelevant
        hout = (t & 1) ? hbuf1 : hbuf0;
        lstm_step<<<256, 256, 0, stream>>>(hin, hout, cst, Wp, x, t,
                                           wgx, wix, wfx, wox, bg, bi, bf, bo);
    }
    logits_kernel<<<256, 256, 0, stream>>>(hbuf1, wph, bp, out);  // t=127 wrote hbuf1
}